// Round 1
// baseline (944.170 us; speedup 1.0000x reference)
//
#include <hip/hip_runtime.h>
#include <stdint.h>

#define AS1 __attribute__((address_space(1)))
#define AS3 __attribute__((address_space(3)))

typedef __bf16 bf16;
typedef __bf16 bf16x2 __attribute__((ext_vector_type(2)));
typedef __bf16 bf16x4v __attribute__((ext_vector_type(4)));
typedef __bf16 bf16x8 __attribute__((ext_vector_type(8)));
typedef float f32x4 __attribute__((ext_vector_type(4)));

#define BN_EPS 1e-5f

__device__ __forceinline__ float bf_lo(uint32_t u) {
    union { uint32_t i; float f; } c; c.i = u << 16; return c.f;
}
__device__ __forceinline__ float bf_hi(uint32_t u) {
    union { uint32_t i; float f; } c; c.i = u & 0xffff0000u; return c.f;
}

// ---- convert fp32 -> bf16, 4 elems/thread ----
__global__ void k_cvt_bf16(const float* __restrict__ src, bf16* __restrict__ dst, int n4) {
    int g = blockIdx.x * blockDim.x + threadIdx.x;
    if (g >= n4) return;
    float4 v = ((const float4*)src)[g];
    bf16x4v o; o[0] = (bf16)v.x; o[1] = (bf16)v.y; o[2] = (bf16)v.z; o[3] = (bf16)v.w;
    ((bf16x4v*)dst)[g] = o;
}

// ---- weights -> bf16, transposed to [col][k] for MFMA B-operand staging ----
__global__ void k_prep_w(const float* __restrict__ Wl0, const float* __restrict__ Wr0,
                         const float* __restrict__ Wl1, const float* __restrict__ Wr1,
                         const float* __restrict__ Wl2, const float* __restrict__ Wr2,
                         bf16* __restrict__ Bt0, bf16* __restrict__ Bt1, bf16* __restrict__ Bt2) {
    int idx = blockIdx.x * 256 + threadIdx.x;   // 32768 threads: c in [0,128), k in [0,256)
    int c = idx >> 8, k = idx & 255;
    float v0 = (k < 128) ? Wl0[k * 128 + c] : Wr0[(k - 128) * 128 + c];
    Bt0[c * 256 + k] = (bf16)v0;
    float v1 = (k < 128) ? Wl1[k * 128 + c] : Wr1[(k - 128) * 128 + c];
    Bt1[c * 256 + k] = (bf16)v1;
    if (k < 128) {
        float v2 = 0.f;
        if (c < 47)      v2 = Wl2[k * 47 + c];
        else if (c < 94) v2 = Wr2[k * 47 + (c - 47)];
        Bt2[c * 128 + k] = (bf16)v2;
    }
}

// ---- CSR build ----
__global__ void k_count(const int* __restrict__ ei, int* __restrict__ deg, int E) {
    int e = blockIdx.x * blockDim.x + threadIdx.x;
    if (e < E) atomicAdd(&deg[ei[E + e]], 1);
}

__global__ void k_scan(const int* __restrict__ deg, int* __restrict__ row_ptr,
                       float* __restrict__ inv_deg, int n) {
    __shared__ int wsum[16];
    int tid = threadIdx.x, lane = tid & 63, wid = tid >> 6;
    if (tid == 0) row_ptr[0] = 0;
    int carry = 0;
    for (int base = 0; base < n; base += 1024) {
        int i = base + tid;
        int d0 = (i < n) ? deg[i] : 0;
        int v = d0;
        #pragma unroll
        for (int d = 1; d < 64; d <<= 1) {
            int t = __shfl_up(v, d, 64);
            if (lane >= d) v += t;
        }
        if (lane == 63) wsum[wid] = v;
        __syncthreads();
        if (tid < 16) {
            int s = wsum[tid];
            #pragma unroll
            for (int d = 1; d < 16; d <<= 1) {
                int t = __shfl_up(s, d, 64);
                if (tid >= d) s += t;
            }
            wsum[tid] = s;
        }
        __syncthreads();
        int wpref = (wid > 0) ? wsum[wid - 1] : 0;
        int incl = v + wpref + carry;
        if (i < n) {
            row_ptr[i + 1] = incl;
            inv_deg[i] = 1.0f / (float)(d0 > 1 ? d0 : 1);
        }
        carry += wsum[15];
        __syncthreads();
    }
}

__global__ void k_fill(const int* __restrict__ ei, const int* __restrict__ row_ptr,
                       int* __restrict__ fil, int* __restrict__ col_idx, int E) {
    int e = blockIdx.x * blockDim.x + threadIdx.x;
    if (e >= E) return;
    int s = ei[e], d = ei[E + e];
    int p = atomicAdd(&fil[d], 1);
    col_idx[row_ptr[d] + p] = s;
}

// ---- mean-aggregate: one wave per node, lane owns 2 features (bf16x2) ----
__global__ void k_aggregate(const bf16* __restrict__ src, bf16* __restrict__ dst,
                            const int* __restrict__ row_ptr, const int* __restrict__ col_idx,
                            const float* __restrict__ inv_deg, int n) {
    int node = blockIdx.x * 4 + (threadIdx.x >> 6);
    int lane = threadIdx.x & 63;
    if (node >= n) return;
    int e0 = row_ptr[node], e1 = row_ptr[node + 1];
    int off = lane << 1;
    float f0 = 0.f, f1 = 0.f;
    int e = e0;
    for (; e + 1 < e1; e += 2) {
        int s0 = col_idx[e], s1 = col_idx[e + 1];
        uint32_t u0 = *(const uint32_t*)(src + s0 * 128 + off);
        uint32_t u1 = *(const uint32_t*)(src + s1 * 128 + off);
        f0 += bf_lo(u0) + bf_lo(u1);
        f1 += bf_hi(u0) + bf_hi(u1);
    }
    if (e < e1) {
        int s0 = col_idx[e];
        uint32_t u0 = *(const uint32_t*)(src + s0 * 128 + off);
        f0 += bf_lo(u0);
        f1 += bf_hi(u0);
    }
    float inv = inv_deg[node];
    bf16x2 o; o[0] = (bf16)(f0 * inv); o[1] = (bf16)(f1 * inv);
    *(bf16x2*)(dst + node * 128 + off) = o;
}

// ---- MFMA GEMM: out[M x ncols] = [A1|A2] @ Bt^T + bias ----
// 128x128 output tile / block (256 thr, 4 waves; wave = 32 rows x 128 cols).
// LDS frag-major layout [tile16][quad][row16][8] == exactly global_load_lds's
// lane*16B contiguous pattern -> conflict-free ds_read_b128.
__global__ __launch_bounds__(256) void k_gemm(
    const bf16* __restrict__ A1, const bf16* __restrict__ A2, const bf16* __restrict__ Bt,
    const float* __restrict__ bias, float* __restrict__ out,
    int M, int ncols, int ldc, int cps, int chunks, int ldb) {
    __shared__ __attribute__((aligned(16))) bf16 sA[4096];
    __shared__ __attribute__((aligned(16))) bf16 sB[4096];
    const int tid = threadIdx.x;
    const int w = tid >> 6, l = tid & 63;
    const int q = l >> 4, r = l & 15;
    const int r0 = blockIdx.x * 128;
    f32x4 acc[2][8];
    #pragma unroll
    for (int i = 0; i < 2; ++i)
        #pragma unroll
        for (int j = 0; j < 8; ++j) { acc[i][j][0] = 0.f; acc[i][j][1] = 0.f; acc[i][j][2] = 0.f; acc[i][j][3] = 0.f; }

    for (int c = 0; c < chunks; ++c) {
        const bf16* As = (c < cps) ? A1 : A2;
        const int ka = (c < cps ? c : c - cps) * 32;
        __syncthreads();
        #pragma unroll
        for (int i = 0; i < 2; ++i) {
            const int T = w * 2 + i;
            const bf16* ga = As + (r0 + T * 16 + r) * 128 + ka + q * 8;
            const bf16* gb = Bt + (T * 16 + r) * ldb + c * 32 + q * 8;
            uint32_t la = (uint32_t)(uintptr_t)(&sA[T * 512]);
            uint32_t lb = (uint32_t)(uintptr_t)(&sB[T * 512]);
            __builtin_amdgcn_global_load_lds((AS1 uint32_t*)(uintptr_t)ga, (AS3 uint32_t*)la, 16, 0, 0);
            __builtin_amdgcn_global_load_lds((AS1 uint32_t*)(uintptr_t)gb, (AS3 uint32_t*)lb, 16, 0, 0);
        }
        __syncthreads();
        bf16x8 af0 = *(const bf16x8*)&sA[(w * 2 + 0) * 512 + q * 128 + r * 8];
        bf16x8 af1 = *(const bf16x8*)&sA[(w * 2 + 1) * 512 + q * 128 + r * 8];
        #pragma unroll
        for (int ct = 0; ct < 8; ++ct) {
            bf16x8 bv = *(const bf16x8*)&sB[ct * 512 + q * 128 + r * 8];
            acc[0][ct] = __builtin_amdgcn_mfma_f32_16x16x32_bf16(af0, bv, acc[0][ct], 0, 0, 0);
            acc[1][ct] = __builtin_amdgcn_mfma_f32_16x16x32_bf16(af1, bv, acc[1][ct], 0, 0, 0);
        }
    }
    #pragma unroll
    for (int rt = 0; rt < 2; ++rt) {
        #pragma unroll
        for (int ct = 0; ct < 8; ++ct) {
            int col = ct * 16 + r;
            if (col >= ncols) continue;
            float bv = bias ? bias[col] : 0.f;
            #pragma unroll
            for (int j = 0; j < 4; ++j) {
                int row = r0 + w * 32 + rt * 16 + q * 4 + j;
                if (row < M) out[(size_t)row * ldc + col] = acc[rt][ct][j] + bv;
            }
        }
    }
}

// ---- BN stats: per-column sum & sumsq ----
__global__ void k_bn_stats(const float* __restrict__ h, float* __restrict__ sums, int n) {
    __shared__ float s1[256], s2[256];
    int t = threadIdx.x;
    int col = t & 127, half = t >> 7;
    int base = blockIdx.x * 128;
    float s = 0.f, q = 0.f;
    for (int i = half; i < 128; i += 2) {
        int row = base + i;
        if (row < n) {
            float v = h[row * 128 + col];
            s += v; q += v * v;
        }
    }
    s1[t] = s; s2[t] = q;
    __syncthreads();
    if (t < 128) {
        atomicAdd(&sums[t], s1[t] + s1[t + 128]);
        atomicAdd(&sums[128 + t], s2[t] + s2[t + 128]);
    }
}

// ---- BN apply + ReLU -> bf16 ----
__global__ void k_bn_apply(const float* __restrict__ h, const float* __restrict__ sums,
                           const float* __restrict__ gma, const float* __restrict__ bta,
                           bf16* __restrict__ out, int n) {
    int g = blockIdx.x * blockDim.x + threadIdx.x;
    int row = g >> 6, c2 = g & 63;
    if (row >= n) return;
    int col = c2 << 1;
    float invn = 1.0f / (float)n;
    float mu0 = sums[col] * invn, mu1 = sums[col + 1] * invn;
    float v0 = sums[128 + col] * invn - mu0 * mu0;
    float v1 = sums[128 + col + 1] * invn - mu1 * mu1;
    float sc0 = gma[col] * rsqrtf(v0 + BN_EPS);
    float sc1 = gma[col + 1] * rsqrtf(v1 + BN_EPS);
    float sh0 = bta[col] - mu0 * sc0;
    float sh1 = bta[col + 1] - mu1 * sc1;
    float2 hv = *(const float2*)(h + row * 128 + col);
    float r0 = fmaxf(hv.x * sc0 + sh0, 0.f);
    float r1 = fmaxf(hv.y * sc1 + sh1, 0.f);
    bf16x2 o; o[0] = (bf16)r0; o[1] = (bf16)r1;
    *(bf16x2*)(out + row * 128 + col) = o;
}

// ---- final: gather-mean of yl (cols 0..46), + yr (cols 47..93) + bl2, log_softmax ----
__global__ void k_final(const float* __restrict__ yy, const int* __restrict__ row_ptr,
                        const int* __restrict__ col_idx, const float* __restrict__ inv_deg,
                        const float* __restrict__ bl2, float* __restrict__ out, int n) {
    int node = blockIdx.x * 4 + (threadIdx.x >> 6);
    int c = threadIdx.x & 63;
    if (node >= n) return;
    int e0 = row_ptr[node], e1 = row_ptr[node + 1];
    bool valid = (c < 47);
    float acc = 0.f;
    for (int e = e0; e < e1; ++e) {
        int s = col_idx[e];
        if (valid) acc += yy[s * 96 + c];
    }
    float val = valid ? (acc * inv_deg[node] + yy[node * 96 + 47 + c] + bl2[c]) : -__builtin_inff();
    float m = val;
    #pragma unroll
    for (int o = 32; o > 0; o >>= 1) m = fmaxf(m, __shfl_xor(m, o, 64));
    float ex = valid ? expf(val - m) : 0.f;
    float sum = ex;
    #pragma unroll
    for (int o = 32; o > 0; o >>= 1) sum += __shfl_xor(sum, o, 64);
    if (valid) out[node * 47 + c] = val - m - logf(sum);
}

extern "C" void kernel_launch(void* const* d_in, const int* in_sizes, int n_in,
                              void* d_out, int out_size, void* d_ws, size_t ws_size,
                              hipStream_t stream) {
    const float* x   = (const float*)d_in[0];
    const int*   ei  = (const int*)d_in[1];
    const float* Wl0 = (const float*)d_in[2];
    const float* bl0 = (const float*)d_in[3];
    const float* Wr0 = (const float*)d_in[4];
    const float* g0  = (const float*)d_in[5];
    const float* be0 = (const float*)d_in[6];
    const float* Wl1 = (const float*)d_in[7];
    const float* bl1 = (const float*)d_in[8];
    const float* Wr1 = (const float*)d_in[9];
    const float* g1  = (const float*)d_in[10];
    const float* be1 = (const float*)d_in[11];
    const float* Wl2 = (const float*)d_in[12];
    const float* bl2 = (const float*)d_in[13];
    const float* Wr2 = (const float*)d_in[14];
    float* out = (float*)d_out;

    const int N  = in_sizes[0] / 128;
    const int E  = in_sizes[1] / 2;
    const int NP = ((N + 127) / 128) * 128;

    char* p = (char*)d_ws;
    size_t off = 0;
    auto alloc = [&](size_t b) { char* r = p + off; off += (b + 255) & ~(size_t)255; return r; };
    int*   deg     = (int*)alloc((size_t)N * 4);
    int*   fil     = (int*)alloc((size_t)N * 4);
    int*   row_ptr = (int*)alloc((size_t)(N + 1) * 4);
    float* invd    = (float*)alloc((size_t)N * 4);
    int*   col_idx = (int*)alloc((size_t)E * 4);
    float* bnsum   = (float*)alloc(512 * 4);
    bf16*  x_bf    = (bf16*)alloc((size_t)NP * 128 * 2);
    bf16*  aggbf   = (bf16*)alloc((size_t)NP * 128 * 2);
    bf16*  hbf     = (bf16*)alloc((size_t)NP * 128 * 2);
    float* bufF    = (float*)alloc((size_t)NP * 128 * 4);
    bf16*  Bt0     = (bf16*)alloc(128 * 256 * 2);
    bf16*  Bt1     = (bf16*)alloc(128 * 256 * 2);
    bf16*  Bt2     = (bf16*)alloc(128 * 128 * 2);

    hipMemsetAsync(deg, 0, (size_t)N * 4, stream);
    hipMemsetAsync(fil, 0, (size_t)N * 4, stream);
    hipMemsetAsync(bnsum, 0, 512 * 4, stream);

    k_prep_w<<<128, 256, 0, stream>>>(Wl0, Wr0, Wl1, Wr1, Wl2, Wr2, Bt0, Bt1, Bt2);
    int n4 = N * 128 / 4;
    k_cvt_bf16<<<(n4 + 255) / 256, 256, 0, stream>>>(x, x_bf, n4);
    k_count<<<(E + 255) / 256, 256, 0, stream>>>(ei, deg, E);
    k_scan<<<1, 1024, 0, stream>>>(deg, row_ptr, invd, N);
    k_fill<<<(E + 255) / 256, 256, 0, stream>>>(ei, row_ptr, fil, col_idx, E);

    int aggBlocks  = (N + 3) / 4;
    int gemmBlocks = NP / 128;

    // Layer 0
    k_aggregate<<<aggBlocks, 256, 0, stream>>>(x_bf, aggbf, row_ptr, col_idx, invd, N);
    k_gemm<<<gemmBlocks, 256, 0, stream>>>(aggbf, x_bf, Bt0, bl0, bufF, N, 128, 128, 4, 8, 256);
    k_bn_stats<<<(N + 127) / 128, 256, 0, stream>>>(bufF, bnsum, N);
    k_bn_apply<<<(N * 64 + 255) / 256, 256, 0, stream>>>(bufF, bnsum, g0, be0, hbf, N);
    // Layer 1
    k_aggregate<<<aggBlocks, 256, 0, stream>>>(hbf, aggbf, row_ptr, col_idx, invd, N);
    k_gemm<<<gemmBlocks, 256, 0, stream>>>(aggbf, hbf, Bt1, bl1, bufF, N, 128, 128, 4, 8, 256);
    k_bn_stats<<<(N + 127) / 128, 256, 0, stream>>>(bufF, bnsum + 256, N);
    k_bn_apply<<<(N * 64 + 255) / 256, 256, 0, stream>>>(bufF, bnsum + 256, g1, be1, hbf, N);
    // Layer 2: project to [yl|yr] (94 cols, ldc 96), then gather+softmax
    k_gemm<<<gemmBlocks, 256, 0, stream>>>(hbf, hbf, Bt2, nullptr, bufF, N, 94, 96, 4, 4, 128);
    k_final<<<aggBlocks, 256, 0, stream>>>(bufF, row_ptr, col_idx, invd, bl2, out, N);
}

// Round 2
// 719.751 us; speedup vs baseline: 1.3118x; 1.3118x over previous
//
#include <hip/hip_runtime.h>
#include <stdint.h>

#define AS1 __attribute__((address_space(1)))
#define AS3 __attribute__((address_space(3)))

typedef __bf16 bf16;
typedef __bf16 bf16x2 __attribute__((ext_vector_type(2)));
typedef __bf16 bf16x4v __attribute__((ext_vector_type(4)));
typedef __bf16 bf16x8 __attribute__((ext_vector_type(8)));
typedef float f32x4 __attribute__((ext_vector_type(4)));

#define BN_EPS 1e-5f

__device__ __forceinline__ float bf_lo(uint32_t u) {
    union { uint32_t i; float f; } c; c.i = u << 16; return c.f;
}
__device__ __forceinline__ float bf_hi(uint32_t u) {
    union { uint32_t i; float f; } c; c.i = u & 0xffff0000u; return c.f;
}

// ---- convert fp32 -> bf16, 4 elems/thread ----
__global__ void k_cvt_bf16(const float* __restrict__ src, bf16* __restrict__ dst, int n4) {
    int g = blockIdx.x * blockDim.x + threadIdx.x;
    if (g >= n4) return;
    float4 v = ((const float4*)src)[g];
    bf16x4v o; o[0] = (bf16)v.x; o[1] = (bf16)v.y; o[2] = (bf16)v.z; o[3] = (bf16)v.w;
    ((bf16x4v*)dst)[g] = o;
}

// ---- weights -> bf16, transposed to [col][k] for MFMA B-operand staging ----
__global__ void k_prep_w(const float* __restrict__ Wl0, const float* __restrict__ Wr0,
                         const float* __restrict__ Wl1, const float* __restrict__ Wr1,
                         const float* __restrict__ Wl2, const float* __restrict__ Wr2,
                         bf16* __restrict__ Bt0, bf16* __restrict__ Bt1, bf16* __restrict__ Bt2) {
    int idx = blockIdx.x * 256 + threadIdx.x;   // 32768 threads: c in [0,128), k in [0,256)
    int c = idx >> 8, k = idx & 255;
    float v0 = (k < 128) ? Wl0[k * 128 + c] : Wr0[(k - 128) * 128 + c];
    Bt0[c * 256 + k] = (bf16)v0;
    float v1 = (k < 128) ? Wl1[k * 128 + c] : Wr1[(k - 128) * 128 + c];
    Bt1[c * 256 + k] = (bf16)v1;
    if (k < 128) {
        float v2 = 0.f;
        if (c < 47)      v2 = Wl2[k * 47 + c];
        else if (c < 94) v2 = Wr2[k * 47 + (c - 47)];
        Bt2[c * 128 + k] = (bf16)v2;
    }
}

// ---- CSR build ----
__global__ void k_count(const int* __restrict__ ei, int* __restrict__ deg, int E) {
    int e = blockIdx.x * blockDim.x + threadIdx.x;
    if (e < E) atomicAdd(&deg[ei[E + e]], 1);
}

// grid-wide scan, stage 1: per-block (1024) inclusive scan + block total
__global__ void k_scan1(const int* __restrict__ deg, int* __restrict__ row_ptr,
                        float* __restrict__ inv_deg, int* __restrict__ partials, int n) {
    __shared__ int wsum[16];
    int tid = threadIdx.x, lane = tid & 63, wid = tid >> 6;
    int i = blockIdx.x * 1024 + tid;
    int d0 = (i < n) ? deg[i] : 0;
    int v = d0;
    #pragma unroll
    for (int d = 1; d < 64; d <<= 1) {
        int t = __shfl_up(v, d, 64);
        if (lane >= d) v += t;
    }
    if (lane == 63) wsum[wid] = v;
    __syncthreads();
    if (tid < 16) {
        int s = wsum[tid];
        #pragma unroll
        for (int d = 1; d < 16; d <<= 1) {
            int t = __shfl_up(s, d, 64);
            if (tid >= d) s += t;
        }
        wsum[tid] = s;
    }
    __syncthreads();
    int incl = v + ((wid > 0) ? wsum[wid - 1] : 0);
    if (i < n) {
        row_ptr[i + 1] = incl;
        inv_deg[i] = 1.0f / (float)(d0 > 1 ? d0 : 1);
    }
    if (tid == 1023) partials[blockIdx.x] = incl;
}

// stage 2: single block scans block totals -> exclusive offsets
__global__ void k_scan2(int* __restrict__ partials, int nb) {
    __shared__ int wtot[2];
    int t = threadIdx.x;
    int carry = 0;
    for (int base = 0; base < nb; base += 128) {
        int idx = base + t;
        int p = (idx < nb) ? partials[idx] : 0;
        int v = p;
        #pragma unroll
        for (int d = 1; d < 64; d <<= 1) {
            int q = __shfl_up(v, d, 64);
            if ((t & 63) >= d) v += q;
        }
        if ((t & 63) == 63) wtot[t >> 6] = v;
        __syncthreads();
        int add = (t >> 6) ? wtot[0] : 0;
        int incl = v + add + carry;
        if (idx < nb) partials[idx] = incl - p;
        carry += wtot[0] + wtot[1];
        __syncthreads();
    }
}

// stage 3: add block offsets
__global__ void k_scan3(int* __restrict__ row_ptr, const int* __restrict__ partials, int n) {
    int i = blockIdx.x * 1024 + threadIdx.x;
    if (i < n) row_ptr[i + 1] += partials[i >> 10];
    if (i == 0) row_ptr[0] = 0;
}

__global__ void k_fill(const int* __restrict__ ei, const int* __restrict__ row_ptr,
                       int* __restrict__ fil, int* __restrict__ col_idx, int E) {
    int e = blockIdx.x * blockDim.x + threadIdx.x;
    if (e >= E) return;
    int s = ei[e], d = ei[E + e];
    int p = atomicAdd(&fil[d], 1);
    col_idx[row_ptr[d] + p] = s;
}

// ---- mean-aggregate: one wave per node, lane owns 2 features, edge loop x4 ----
__global__ void k_aggregate(const bf16* __restrict__ src, bf16* __restrict__ dst,
                            const int* __restrict__ row_ptr, const int* __restrict__ col_idx,
                            const float* __restrict__ inv_deg, int n) {
    int node = blockIdx.x * 4 + (threadIdx.x >> 6);
    int lane = threadIdx.x & 63;
    if (node >= n) return;
    int e0 = row_ptr[node], e1 = row_ptr[node + 1];
    const bf16* sp = src + (lane << 1);
    float f0 = 0.f, f1 = 0.f;
    int e = e0;
    for (; e + 3 < e1; e += 4) {
        int s0 = col_idx[e], s1 = col_idx[e + 1], s2 = col_idx[e + 2], s3 = col_idx[e + 3];
        uint32_t u0 = *(const uint32_t*)(sp + (size_t)s0 * 128);
        uint32_t u1 = *(const uint32_t*)(sp + (size_t)s1 * 128);
        uint32_t u2 = *(const uint32_t*)(sp + (size_t)s2 * 128);
        uint32_t u3 = *(const uint32_t*)(sp + (size_t)s3 * 128);
        f0 += (bf_lo(u0) + bf_lo(u1)) + (bf_lo(u2) + bf_lo(u3));
        f1 += (bf_hi(u0) + bf_hi(u1)) + (bf_hi(u2) + bf_hi(u3));
    }
    for (; e < e1; ++e) {
        uint32_t u0 = *(const uint32_t*)(sp + (size_t)col_idx[e] * 128);
        f0 += bf_lo(u0);
        f1 += bf_hi(u0);
    }
    float inv = inv_deg[node];
    bf16x2 o; o[0] = (bf16)(f0 * inv); o[1] = (bf16)(f1 * inv);
    *(bf16x2*)(dst + (size_t)node * 128 + (lane << 1)) = o;
}

// ---- MFMA GEMM: out[M x ncols] = [A1|A2] @ Bt^T (+ bias) ----
// mode 0 (ylbf==nullptr): fp32 out, ldc stride, +bias.
// mode 1 (layer 2): cols 0..46 -> ylbf (bf16, row stride 64); cols 47..93 -> outF (fp32, stride 48).
__global__ __launch_bounds__(256) void k_gemm(
    const bf16* __restrict__ A1, const bf16* __restrict__ A2, const bf16* __restrict__ Bt,
    const float* __restrict__ bias, float* __restrict__ outF, bf16* __restrict__ ylbf,
    int M, int ncols, int ldc, int cps, int chunks, int ldb) {
    __shared__ __attribute__((aligned(16))) bf16 sA[4096];
    __shared__ __attribute__((aligned(16))) bf16 sB[4096];
    const int tid = threadIdx.x;
    const int w = tid >> 6, l = tid & 63;
    const int q = l >> 4, r = l & 15;
    const int r0 = blockIdx.x * 128;
    f32x4 acc[2][8];
    #pragma unroll
    for (int i = 0; i < 2; ++i)
        #pragma unroll
        for (int j = 0; j < 8; ++j) { acc[i][j][0] = 0.f; acc[i][j][1] = 0.f; acc[i][j][2] = 0.f; acc[i][j][3] = 0.f; }

    for (int c = 0; c < chunks; ++c) {
        const bf16* As = (c < cps) ? A1 : A2;
        const int ka = (c < cps ? c : c - cps) * 32;
        __syncthreads();
        #pragma unroll
        for (int i = 0; i < 2; ++i) {
            const int T = w * 2 + i;
            const bf16* ga = As + (size_t)(r0 + T * 16 + r) * 128 + ka + q * 8;
            const bf16* gb = Bt + (T * 16 + r) * ldb + c * 32 + q * 8;
            uint32_t la = (uint32_t)(uintptr_t)(&sA[T * 512]);
            uint32_t lb = (uint32_t)(uintptr_t)(&sB[T * 512]);
            __builtin_amdgcn_global_load_lds((AS1 uint32_t*)(uintptr_t)ga, (AS3 uint32_t*)la, 16, 0, 0);
            __builtin_amdgcn_global_load_lds((AS1 uint32_t*)(uintptr_t)gb, (AS3 uint32_t*)lb, 16, 0, 0);
        }
        __syncthreads();
        bf16x8 af0 = *(const bf16x8*)&sA[(w * 2 + 0) * 512 + q * 128 + r * 8];
        bf16x8 af1 = *(const bf16x8*)&sA[(w * 2 + 1) * 512 + q * 128 + r * 8];
        #pragma unroll
        for (int ct = 0; ct < 8; ++ct) {
            bf16x8 bv = *(const bf16x8*)&sB[ct * 512 + q * 128 + r * 8];
            acc[0][ct] = __builtin_amdgcn_mfma_f32_16x16x32_bf16(af0, bv, acc[0][ct], 0, 0, 0);
            acc[1][ct] = __builtin_amdgcn_mfma_f32_16x16x32_bf16(af1, bv, acc[1][ct], 0, 0, 0);
        }
    }
    if (ylbf == nullptr) {
        #pragma unroll
        for (int rt = 0; rt < 2; ++rt) {
            #pragma unroll
            for (int ct = 0; ct < 8; ++ct) {
                int col = ct * 16 + r;
                if (col >= ncols) continue;
                float bv = bias ? bias[col] : 0.f;
                #pragma unroll
                for (int j = 0; j < 4; ++j) {
                    int row = r0 + w * 32 + rt * 16 + q * 4 + j;
                    if (row < M) outF[(size_t)row * ldc + col] = acc[rt][ct][j] + bv;
                }
            }
        }
    } else {
        #pragma unroll
        for (int rt = 0; rt < 2; ++rt) {
            #pragma unroll
            for (int ct = 0; ct < 8; ++ct) {
                int col = ct * 16 + r;
                #pragma unroll
                for (int j = 0; j < 4; ++j) {
                    int row = r0 + w * 32 + rt * 16 + q * 4 + j;
                    if (row >= M) continue;
                    if (col < 47)      ylbf[(size_t)row * 64 + col] = (bf16)acc[rt][ct][j];
                    else if (col < 94) outF[(size_t)row * 48 + (col - 47)] = acc[rt][ct][j];
                }
            }
        }
    }
}

// ---- BN stats: per-column sum & sumsq ----
__global__ void k_bn_stats(const float* __restrict__ h, float* __restrict__ sums, int n) {
    __shared__ float s1[256], s2[256];
    int t = threadIdx.x;
    int col = t & 127, half = t >> 7;
    int base = blockIdx.x * 128;
    float s = 0.f, q = 0.f;
    for (int i = half; i < 128; i += 2) {
        int row = base + i;
        if (row < n) {
            float v = h[(size_t)row * 128 + col];
            s += v; q += v * v;
        }
    }
    s1[t] = s; s2[t] = q;
    __syncthreads();
    if (t < 128) {
        atomicAdd(&sums[t], s1[t] + s1[t + 128]);
        atomicAdd(&sums[128 + t], s2[t] + s2[t + 128]);
    }
}

// ---- BN apply + ReLU -> bf16 ----
__global__ void k_bn_apply(const float* __restrict__ h, const float* __restrict__ sums,
                           const float* __restrict__ gma, const float* __restrict__ bta,
                           bf16* __restrict__ out, int n) {
    int g = blockIdx.x * blockDim.x + threadIdx.x;
    int row = g >> 6, c2 = g & 63;
    if (row >= n) return;
    int col = c2 << 1;
    float invn = 1.0f / (float)n;
    float mu0 = sums[col] * invn, mu1 = sums[col + 1] * invn;
    float v0 = sums[128 + col] * invn - mu0 * mu0;
    float v1 = sums[128 + col + 1] * invn - mu1 * mu1;
    float sc0 = gma[col] * rsqrtf(v0 + BN_EPS);
    float sc1 = gma[col + 1] * rsqrtf(v1 + BN_EPS);
    float sh0 = bta[col] - mu0 * sc0;
    float sh1 = bta[col + 1] - mu1 * sc1;
    float2 hv = *(const float2*)(h + (size_t)row * 128 + col);
    float r0 = fmaxf(hv.x * sc0 + sh0, 0.f);
    float r1 = fmaxf(hv.y * sc1 + sh1, 0.f);
    bf16x2 o; o[0] = (bf16)r0; o[1] = (bf16)r1;
    *(bf16x2*)(out + (size_t)row * 128 + col) = o;
}

// ---- final: gather-mean of yl (bf16, 64-wide rows) + yr + bl2, log_softmax ----
__global__ void k_final(const bf16* __restrict__ yl, const float* __restrict__ yr,
                        const int* __restrict__ row_ptr, const int* __restrict__ col_idx,
                        const float* __restrict__ inv_deg, const float* __restrict__ bl2,
                        float* __restrict__ out, int n) {
    int node = blockIdx.x * 4 + (threadIdx.x >> 6);
    int c = threadIdx.x & 63;
    if (node >= n) return;
    int e0 = row_ptr[node], e1 = row_ptr[node + 1];
    bool valid = (c < 47);
    const bf16* ylc = yl + c;
    float acc = 0.f;
    int e = e0;
    for (; e + 3 < e1; e += 4) {
        int s0 = col_idx[e], s1 = col_idx[e + 1], s2 = col_idx[e + 2], s3 = col_idx[e + 3];
        float v0 = (float)ylc[(size_t)s0 * 64];
        float v1 = (float)ylc[(size_t)s1 * 64];
        float v2 = (float)ylc[(size_t)s2 * 64];
        float v3 = (float)ylc[(size_t)s3 * 64];
        acc += (v0 + v1) + (v2 + v3);
    }
    for (; e < e1; ++e) acc += (float)ylc[(size_t)col_idx[e] * 64];
    float yv = valid ? yr[(size_t)node * 48 + c] : 0.f;
    float bv = valid ? bl2[c] : 0.f;
    float val = valid ? (acc * inv_deg[node] + yv + bv) : -__builtin_inff();
    float m = val;
    #pragma unroll
    for (int o = 32; o > 0; o >>= 1) m = fmaxf(m, __shfl_xor(m, o, 64));
    float ex = valid ? expf(val - m) : 0.f;
    float sum = ex;
    #pragma unroll
    for (int o = 32; o > 0; o >>= 1) sum += __shfl_xor(sum, o, 64);
    if (valid) out[(size_t)node * 47 + c] = val - m - logf(sum);
}

extern "C" void kernel_launch(void* const* d_in, const int* in_sizes, int n_in,
                              void* d_out, int out_size, void* d_ws, size_t ws_size,
                              hipStream_t stream) {
    const float* x   = (const float*)d_in[0];
    const int*   ei  = (const int*)d_in[1];
    const float* Wl0 = (const float*)d_in[2];
    const float* bl0 = (const float*)d_in[3];
    const float* Wr0 = (const float*)d_in[4];
    const float* g0  = (const float*)d_in[5];
    const float* be0 = (const float*)d_in[6];
    const float* Wl1 = (const float*)d_in[7];
    const float* bl1 = (const float*)d_in[8];
    const float* Wr1 = (const float*)d_in[9];
    const float* g1  = (const float*)d_in[10];
    const float* be1 = (const float*)d_in[11];
    const float* Wl2 = (const float*)d_in[12];
    const float* bl2 = (const float*)d_in[13];
    const float* Wr2 = (const float*)d_in[14];
    float* out = (float*)d_out;

    const int N  = in_sizes[0] / 128;
    const int E  = in_sizes[1] / 2;
    const int NP = ((N + 127) / 128) * 128;

    char* p = (char*)d_ws;
    size_t off = 0;
    auto alloc = [&](size_t b) { char* r = p + off; off += (b + 255) & ~(size_t)255; return r; };
    int*   deg     = (int*)alloc((size_t)N * 4);
    int*   fil     = (int*)alloc((size_t)N * 4);
    int*   row_ptr = (int*)alloc((size_t)(N + 1) * 4);
    float* invd    = (float*)alloc((size_t)N * 4);
    int*   col_idx = (int*)alloc((size_t)E * 4);
    float* bnsum   = (float*)alloc(512 * 4);
    int*   partials= (int*)alloc(1024 * 4);
    bf16*  x_bf    = (bf16*)alloc((size_t)NP * 128 * 2);
    bf16*  aggbf   = (bf16*)alloc((size_t)NP * 128 * 2);
    bf16*  hbf     = (bf16*)alloc((size_t)NP * 128 * 2);
    float* bufF    = (float*)alloc((size_t)NP * 128 * 4);
    bf16*  Bt0     = (bf16*)alloc(128 * 256 * 2);
    bf16*  Bt1     = (bf16*)alloc(128 * 256 * 2);
    bf16*  Bt2     = (bf16*)alloc(128 * 128 * 2);
    // layer-2 outputs alias bufF (free by then): yl bf16 [NP][64], yr fp32 [NP][48]
    bf16*  ylbf = (bf16*)bufF;
    float* yrF  = (float*)((char*)bufF + (size_t)NP * 128);

    hipMemsetAsync(deg, 0, (size_t)N * 4, stream);
    hipMemsetAsync(fil, 0, (size_t)N * 4, stream);
    hipMemsetAsync(bnsum, 0, 512 * 4, stream);

    k_prep_w<<<128, 256, 0, stream>>>(Wl0, Wr0, Wl1, Wr1, Wl2, Wr2, Bt0, Bt1, Bt2);
    int n4 = N * 128 / 4;
    k_cvt_bf16<<<(n4 + 255) / 256, 256, 0, stream>>>(x, x_bf, n4);
    k_count<<<(E + 255) / 256, 256, 0, stream>>>(ei, deg, E);
    int nb = (N + 1023) / 1024;
    k_scan1<<<nb, 1024, 0, stream>>>(deg, row_ptr, invd, partials, N);
    k_scan2<<<1, 128, 0, stream>>>(partials, nb);
    k_scan3<<<nb, 1024, 0, stream>>>(row_ptr, partials, N);
    k_fill<<<(E + 255) / 256, 256, 0, stream>>>(ei, row_ptr, fil, col_idx, E);

    int aggBlocks  = (N + 3) / 4;
    int gemmBlocks = NP / 128;

    // Layer 0
    k_aggregate<<<aggBlocks, 256, 0, stream>>>(x_bf, aggbf, row_ptr, col_idx, invd, N);
    k_gemm<<<gemmBlocks, 256, 0, stream>>>(aggbf, x_bf, Bt0, bl0, bufF, nullptr, N, 128, 128, 4, 8, 256);
    k_bn_stats<<<(N + 127) / 128, 256, 0, stream>>>(bufF, bnsum, N);
    k_bn_apply<<<(N * 64 + 255) / 256, 256, 0, stream>>>(bufF, bnsum, g0, be0, hbf, N);
    // Layer 1
    k_aggregate<<<aggBlocks, 256, 0, stream>>>(hbf, aggbf, row_ptr, col_idx, invd, N);
    k_gemm<<<gemmBlocks, 256, 0, stream>>>(aggbf, hbf, Bt1, bl1, bufF, nullptr, N, 128, 128, 4, 8, 256);
    k_bn_stats<<<(N + 127) / 128, 256, 0, stream>>>(bufF, bnsum + 256, N);
    k_bn_apply<<<(N * 64 + 255) / 256, 256, 0, stream>>>(bufF, bnsum + 256, g1, be1, hbf, N);
    // Layer 2: project to yl (bf16) / yr (fp32), then gather + log_softmax
    k_gemm<<<gemmBlocks, 256, 0, stream>>>(hbf, hbf, Bt2, nullptr, yrF, ylbf, N, 94, 96, 4, 4, 128);
    k_final<<<aggBlocks, 256, 0, stream>>>(ylbf, yrF, row_ptr, col_idx, invd, bl2, out, N);
}